// Round 3
// baseline (401.367 us; speedup 1.0000x reference)
//
#include <hip/hip_runtime.h>

#define OUT_S 7
#define NPTS  49        // 7x7 sample points
#define C_CH  256

__global__ __launch_bounds__(256, 8) void roi_align_fused(
    const float* __restrict__ p2, const float* __restrict__ p3,
    const float* __restrict__ p4, const float* __restrict__ p5,
    const float* __restrict__ prop, const int* __restrict__ Hp,
    const int* __restrict__ Wp, float* __restrict__ out, int K_per_img)
{
    const int n    = blockIdx.x;          // roi index, 0..N-1
    const int lane = threadIdx.x & 63;
    const int wave = threadIdx.x >> 6;    // 0..3 -> channel group of 64
    const int b    = n / K_per_img;       // batch image index

    const float W = (float)Wp[0];
    const float H = (float)Hp[0];

    // box (16B-aligned float4 load, uniform across block)
    const float4 box = reinterpret_cast<const float4*>(prop)[n];
    const float x1 = box.x, y1 = box.y, x2 = box.z, y2 = box.w;

    // level selection — mirror the reference's exact op order:
    // areas = sqrt(max(dx*dy,1e-6)); lev = clip(floor(4 + log2(areas/224)), 2, 5)
    const float area = fmaxf((x2 - x1) * (y2 - y1), 1e-6f);
    const float sqa  = sqrtf(area);
    int lev = (int)floorf(4.0f + log2f(sqa / 224.0f));   // true division, ref order
    lev = min(max(lev, 2), 5);

    const float* fm; int Hf, Wf;
    if      (lev == 2) { fm = p2; Hf = 200; Wf = 200; }
    else if (lev == 3) { fm = p3; Hf = 100; Wf = 100; }
    else if (lev == 4) { fm = p4; Hf = 50;  Wf = 50;  }
    else               { fm = p5; Hf = 25;  Wf = 25;  }

    if (lane >= NPTS) return;             // no barriers anywhere: early-exit is safe
    const int iy = lane / OUT_S;
    const int ix = lane - iy * OUT_S;

    // grid_sample coords, align_corners=True, border padding (reference op order)
    const float x1n = x1 / W * 2.0f - 1.0f;
    const float x2n = x2 / W * 2.0f - 1.0f;
    const float y1n = y1 / H * 2.0f - 1.0f;
    const float y2n = y2 / H * 2.0f - 1.0f;
    const float tx = (float)ix * (1.0f / 6.0f);   // linspace(0,1,7)[ix]
    const float ty = (float)iy * (1.0f / 6.0f);
    const float gx = x1n + (x2n - x1n) * tx;
    const float gy = y1n + (y2n - y1n) * ty;

    float x = (gx + 1.0f) * 0.5f * (float)(Wf - 1);
    float y = (gy + 1.0f) * 0.5f * (float)(Hf - 1);
    x = fminf(fmaxf(x, 0.0f), (float)(Wf - 1));
    y = fminf(fmaxf(y, 0.0f), (float)(Hf - 1));

    const float x0f = floorf(x), y0f = floorf(y);
    const float wx = x - x0f,  wy = y - y0f;
    const int xi0 = (int)x0f,  yi0 = (int)y0f;
    const int xi1 = min(xi0 + 1, Wf - 1);
    const int yi1 = min(yi0 + 1, Hf - 1);

    const float omwx = 1.0f - wx, omwy = 1.0f - wy;

    const int plane = Hf * Wf;            // <= 40000: 32-bit offsets throughout
    // wave w owns channels [64w, 64w+64)
    const float* base = fm + ((size_t)b * C_CH + (size_t)(wave * 64)) * (size_t)plane;
    float*       op   = out + ((size_t)n * C_CH + (size_t)(wave * 64)) * NPTS + lane;

    int o00 = yi0 * Wf + xi0;
    int o01 = yi0 * Wf + xi1;
    int o10 = yi1 * Wf + xi0;
    int o11 = yi1 * Wf + xi1;

    #pragma unroll 4
    for (int k = 0; k < 64; ++k) {
        const float v00 = base[o00];
        const float v01 = base[o01];
        const float v10 = base[o10];
        const float v11 = base[o11];
        o00 += plane; o01 += plane; o10 += plane; o11 += plane;
        // reference's exact two-stage lerp (bit-matching rounding order)
        const float top = v00 * omwx + v01 * wx;
        const float bot = v10 * omwx + v11 * wx;
        const float r   = top * omwy + bot * wy;
        // output written once, never re-read: bypass L2/LLC so the feature
        // maps (217 MB, LLC-fits) stay resident across graph replays
        __builtin_nontemporal_store(r, &op[(size_t)k * NPTS]);
    }
}

extern "C" void kernel_launch(void* const* d_in, const int* in_sizes, int n_in,
                              void* d_out, int out_size, void* d_ws, size_t ws_size,
                              hipStream_t stream) {
    const float* p2   = (const float*)d_in[0];
    const float* p3   = (const float*)d_in[1];
    const float* p4   = (const float*)d_in[2];
    const float* p5   = (const float*)d_in[3];
    const float* prop = (const float*)d_in[4];
    const int*   Hp   = (const int*)d_in[5];
    const int*   Wp   = (const int*)d_in[6];
    float* out = (float*)d_out;

    const int N = in_sizes[4] / 4;                    // B*K rois
    const int B = in_sizes[0] / (C_CH * 200 * 200);   // from p2 = [B,256,200,200]
    const int K = N / (B > 0 ? B : 1);                // proposals per image

    roi_align_fused<<<N, 256, 0, stream>>>(p2, p3, p4, p5, prop, Hp, Wp, out, K);
}